// Round 1
// baseline (1670.908 us; speedup 1.0000x reference)
//
#include <hip/hip_runtime.h>

// NearestNeighborTokenizer: ids = (min_c ||x - c||^2 <= 900) ? argmin_c : -1
// x: [8192, 512] fp32, codes: [16384, 512] fp32, out: [8192] int32
//
// dist^2 = ||x||^2 + ||c||^2 - 2 x.c ; argmin over c only needs score = ||c||^2 - 2 x.c
// ||x||^2 is added at the very end, only for the <=900 threshold test.

#define NTOK   8192
#define NCODES 16384
#define DDIM   512
#define BM 128
#define BN 128
#define BK 16
#define NCHUNK 16
#define CHUNK (NCODES / NCHUNK)   // 1024 codes per block's N-range
#define DIST_THR 900.0f

// ---------------- kernel 1: c2[c] = ||codes[c]||^2 (one wave per code) ------
__global__ __launch_bounds__(256) void nn_c2(const float* __restrict__ codes,
                                             float* __restrict__ c2) {
    int w = threadIdx.x >> 6;
    int lane = threadIdx.x & 63;
    int c = blockIdx.x * 4 + w;
    const float* p = codes + (size_t)c * DDIM + lane * 8;
    float4 v0 = *(const float4*)p;
    float4 v1 = *(const float4*)(p + 4);
    float s = v0.x*v0.x + v0.y*v0.y + v0.z*v0.z + v0.w*v0.w
            + v1.x*v1.x + v1.y*v1.y + v1.z*v1.z + v1.w*v1.w;
    #pragma unroll
    for (int off = 32; off > 0; off >>= 1) s += __shfl_down(s, off);
    if (lane == 0) c2[c] = s;
}

// ---------------- kernel 2: fused GEMM + running argmin ---------------------
// grid = (NTOK/BM, NCHUNK). Each block: 128 tokens x 1024 codes.
// Thread (tx,ty) in 16x16 grid owns rows {ty*4..+3, 64+ty*4..+3},
// cols {tx*4..+3, 64+tx*4..+3} -> 8x8 microtile, fma from float4 LDS reads.
__global__ __launch_bounds__(256) void nn_main(const float* __restrict__ x,
                                               const float* __restrict__ codes,
                                               const float* __restrict__ c2,
                                               float* __restrict__ pmin,
                                               int* __restrict__ pid) {
    __shared__ float As[BK * BM];   // As[k*BM + m]
    __shared__ float Bs[BK * BN];   // Bs[k*BN + n]
    const int tid = threadIdx.x;
    const int tx = tid & 15;
    const int ty = tid >> 4;
    const int m0 = blockIdx.x * BM;
    const int nbase = blockIdx.y * CHUNK;

    float minv[8];
    int   mini[8];
    #pragma unroll
    for (int i = 0; i < 8; ++i) { minv[i] = 3.4e38f; mini[i] = 0; }

    for (int nt = 0; nt < CHUNK / BN; ++nt) {
        const int n0 = nbase + nt * BN;
        float acc[8][8];
        #pragma unroll
        for (int i = 0; i < 8; ++i)
            #pragma unroll
            for (int j = 0; j < 8; ++j) acc[i][j] = 0.0f;

        for (int k0 = 0; k0 < DDIM; k0 += BK) {
            // stage A and B tiles (transpose to k-major for float4 reads)
            #pragma unroll
            for (int r = 0; r < 2; ++r) {
                int f = tid + 256 * r;         // 512 float4 loads per tile
                int kc = f & 3;                // which float4 along BK
                int m  = f >> 2;               // row (token / code)
                float4 va = *(const float4*)(x     + (size_t)(m0 + m) * DDIM + k0 + kc * 4);
                float4 vb = *(const float4*)(codes + (size_t)(n0 + m) * DDIM + k0 + kc * 4);
                As[(kc*4+0)*BM + m] = va.x;
                As[(kc*4+1)*BM + m] = va.y;
                As[(kc*4+2)*BM + m] = va.z;
                As[(kc*4+3)*BM + m] = va.w;
                Bs[(kc*4+0)*BN + m] = vb.x;
                Bs[(kc*4+1)*BN + m] = vb.y;
                Bs[(kc*4+2)*BN + m] = vb.z;
                Bs[(kc*4+3)*BN + m] = vb.w;
            }
            __syncthreads();
            #pragma unroll
            for (int k = 0; k < BK; ++k) {
                float4 a0 = *(const float4*)&As[k*BM + ty*4];
                float4 a1 = *(const float4*)&As[k*BM + 64 + ty*4];
                float4 b0 = *(const float4*)&Bs[k*BN + tx*4];
                float4 b1 = *(const float4*)&Bs[k*BN + 64 + tx*4];
                float a[8] = {a0.x, a0.y, a0.z, a0.w, a1.x, a1.y, a1.z, a1.w};
                float b[8] = {b0.x, b0.y, b0.z, b0.w, b1.x, b1.y, b1.z, b1.w};
                #pragma unroll
                for (int i = 0; i < 8; ++i)
                    #pragma unroll
                    for (int j = 0; j < 8; ++j)
                        acc[i][j] = fmaf(a[i], b[j], acc[i][j]);
            }
            __syncthreads();
        }

        // epilogue: score = ||c||^2 - 2 x.c, update running (min, id).
        // Scan order per row is strictly increasing code index -> strict '<'
        // reproduces jnp.argmin first-occurrence tie-break.
        #pragma unroll
        for (int j = 0; j < 8; ++j) {
            int c = (j < 4) ? (tx*4 + j) : (64 + tx*4 + j - 4);
            float cv = c2[n0 + c];
            #pragma unroll
            for (int i = 0; i < 8; ++i) {
                float s = fmaf(-2.0f, acc[i][j], cv);
                if (s < minv[i]) { minv[i] = s; mini[i] = n0 + c; }
            }
        }
    }

    // block reduce across the 16 tx owning disjoint column sets (LDS reuse)
    float* rmin = As;        // 128*16 floats
    int*   rid  = (int*)Bs;  // 128*16 ints
    #pragma unroll
    for (int i = 0; i < 8; ++i) {
        int r = (i < 4) ? (ty*4 + i) : (64 + ty*4 + i - 4);
        rmin[r*16 + tx] = minv[i];
        rid [r*16 + tx] = mini[i];
    }
    __syncthreads();
    if (tid < BM) {
        float bv = rmin[tid*16];
        int   bi = rid [tid*16];
        #pragma unroll
        for (int t = 1; t < 16; ++t) {
            float v  = rmin[tid*16 + t];
            int   id = rid [tid*16 + t];
            if (v < bv || (v == bv && id < bi)) { bv = v; bi = id; }
        }
        pmin[(size_t)(m0 + tid) * NCHUNK + blockIdx.y] = bv;
        pid [(size_t)(m0 + tid) * NCHUNK + blockIdx.y] = bi;
    }
}

// ---------------- kernel 3: finalize (one wave per token) -------------------
__global__ __launch_bounds__(256) void nn_fin(const float* __restrict__ x,
                                              const float* __restrict__ pmin,
                                              const int* __restrict__ pid,
                                              int* __restrict__ out) {
    int w = threadIdx.x >> 6;
    int lane = threadIdx.x & 63;
    int t = blockIdx.x * 4 + w;
    const float* p = x + (size_t)t * DDIM + lane * 8;
    float4 v0 = *(const float4*)p;
    float4 v1 = *(const float4*)(p + 4);
    float s = v0.x*v0.x + v0.y*v0.y + v0.z*v0.z + v0.w*v0.w
            + v1.x*v1.x + v1.y*v1.y + v1.z*v1.z + v1.w*v1.w;
    #pragma unroll
    for (int off = 32; off > 0; off >>= 1) s += __shfl_down(s, off);
    if (lane == 0) {
        const float* pm = pmin + (size_t)t * NCHUNK;
        const int*   pi = pid  + (size_t)t * NCHUNK;
        float bv = pm[0]; int bi = pi[0];
        #pragma unroll
        for (int c = 1; c < NCHUNK; ++c) {
            float v = pm[c]; int id = pi[c];
            if (v < bv || (v == bv && id < bi)) { bv = v; bi = id; }
        }
        float mind = s + bv;  // ||x||^2 + min(||c||^2 - 2 x.c)
        out[t] = (mind <= DIST_THR) ? bi : -1;
    }
}

extern "C" void kernel_launch(void* const* d_in, const int* in_sizes, int n_in,
                              void* d_out, int out_size, void* d_ws, size_t ws_size,
                              hipStream_t stream) {
    const float* x     = (const float*)d_in[0];
    const float* codes = (const float*)d_in[1];
    int* out = (int*)d_out;

    // workspace layout: c2 (64KB) | pmin (512KB) | pid (512KB)
    float* c2   = (float*)d_ws;
    float* pmin = c2 + NCODES;
    int*   pid  = (int*)(pmin + (size_t)NTOK * NCHUNK);

    nn_c2<<<NCODES / 4, 256, 0, stream>>>(codes, c2);
    dim3 grid(NTOK / BM, NCHUNK);
    nn_main<<<grid, 256, 0, stream>>>(x, codes, c2, pmin, pid);
    nn_fin<<<NTOK / 4, 256, 0, stream>>>(x, pmin, pid, out);
}

// Round 2
// 461.194 us; speedup vs baseline: 3.6230x; 3.6230x over previous
//
#include <hip/hip_runtime.h>

// NearestNeighborTokenizer: ids = (min_c ||x - c||^2 <= 900) ? argmin_c : -1
// x: [8192, 512] fp32, codes: [16384, 512] fp32, out: [8192] int32
//
// R2: fp16x3 MFMA GEMM. x,c scaled by 16 and split into fp16 hi+lo planes,
// pre-swizzled in global memory into MFMA fragment order so the GEMM kernel
// stages tiles with global_load_lds(width=16) and reads fragments with
// ds_read_b128 conflict-free. dot = (hh + hl + lh)/256 in one fp32 acc.
// score = ||c||^2 - 2*dot; ||x||^2 added only at the final threshold test.

#define NTOK   8192
#define NCODES 16384
#define DDIM   512
#define NCHUNK 8
#define CHUNK  2048          // codes per chunk (fits one XCD L2 as fp16 hi+lo)
#define DIST_THR 900.0f

typedef unsigned short u16;
typedef _Float16 half8 __attribute__((ext_vector_type(8)));
typedef float    f32x4 __attribute__((ext_vector_type(4)));

// ---------------- kernel 1: convert + pre-swizzle to fragment order ---------
// Chunk linear index c (8 halfs each):
//   r=c&15, q=(c>>4)&3, g=(c>>6)&7, kit=(c>>9)&15, tile=c>>13
//   row = tile*128 + g*16 + r ; k = kit*32 + q*8
// This makes each (tile,kit) a contiguous 8KB block in exactly the LDS
// fragment layout the GEMM wants (lane L <-> row base+(L&15), k-quad L>>4).
__global__ __launch_bounds__(256) void nn_conv(const float* __restrict__ src,
                                               u16* __restrict__ dh,
                                               u16* __restrict__ dl) {
    int c = blockIdx.x * 256 + threadIdx.x;
    int r = c & 15, q = (c >> 4) & 3, g = (c >> 6) & 7, kit = (c >> 9) & 15;
    int tile = c >> 13;
    int row = tile * 128 + g * 16 + r;
    int k = kit * 32 + q * 8;
    const float* p = src + (size_t)row * DDIM + k;
    float4 v0 = *(const float4*)p;
    float4 v1 = *(const float4*)(p + 4);
    float vv[8] = {v0.x, v0.y, v0.z, v0.w, v1.x, v1.y, v1.z, v1.w};
    u16 hs[8], ls[8];
    #pragma unroll
    for (int j = 0; j < 8; ++j) {
        float sv = vv[j] * 16.0f;              // scale 16: keeps lo out of denorms
        _Float16 h = (_Float16)sv;
        float hf = (float)h;
        _Float16 l = (_Float16)(sv - hf);
        union { _Float16 f; u16 u; } uh, ul;
        uh.f = h; ul.f = l;
        hs[j] = uh.u; ls[j] = ul.u;
    }
    uint4 H, L;
    H.x = hs[0] | ((unsigned)hs[1] << 16); H.y = hs[2] | ((unsigned)hs[3] << 16);
    H.z = hs[4] | ((unsigned)hs[5] << 16); H.w = hs[6] | ((unsigned)hs[7] << 16);
    L.x = ls[0] | ((unsigned)ls[1] << 16); L.y = ls[2] | ((unsigned)ls[3] << 16);
    L.z = ls[4] | ((unsigned)ls[5] << 16); L.w = ls[6] | ((unsigned)ls[7] << 16);
    *(uint4*)(dh + (size_t)c * 8) = H;
    *(uint4*)(dl + (size_t)c * 8) = L;
}

// ---------------- kernel 2: c2[c] = ||codes[c]||^2 (fp32, one wave/code) ----
__global__ __launch_bounds__(256) void nn_c2(const float* __restrict__ codes,
                                             float* __restrict__ c2) {
    int w = threadIdx.x >> 6;
    int lane = threadIdx.x & 63;
    int c = blockIdx.x * 4 + w;
    const float* p = codes + (size_t)c * DDIM + lane * 8;
    float4 v0 = *(const float4*)p;
    float4 v1 = *(const float4*)(p + 4);
    float s = v0.x*v0.x + v0.y*v0.y + v0.z*v0.z + v0.w*v0.w
            + v1.x*v1.x + v1.y*v1.y + v1.z*v1.z + v1.w*v1.w;
    #pragma unroll
    for (int off = 32; off > 0; off >>= 1) s += __shfl_down(s, off);
    if (lane == 0) c2[c] = s;
}

// ---------------- kernel 3: fp16x3 MFMA GEMM + fused argmin -----------------
// grid = 64 m-tiles * 8 chunks, blockIdx.x = mtile*8 + chunk (chunk -> XCD).
// Block: 128 tokens x 2048 codes (16 n-tiles of 128). 4 waves, each 64x64.
// LDS: tiles Ah|Al|Bh|Bl 4*8KB (union with 33KB reduce scratch) + 8KB c2s.
#define SM_C2 33024
__global__ __launch_bounds__(256) void nn_gemm(const u16* __restrict__ xh,
                                               const u16* __restrict__ xl,
                                               const u16* __restrict__ chh,
                                               const u16* __restrict__ cll,
                                               const float* __restrict__ c2,
                                               float* __restrict__ pmin,
                                               int* __restrict__ pid) {
    __shared__ __align__(16) char smem[SM_C2 + CHUNK * 4];
    const int tid = threadIdx.x;
    const int lane = tid & 63;
    const int wave = tid >> 6;
    const int wm = wave & 1;            // wave row  (64-row half)
    const int wn = wave >> 1;           // wave col  (64-col half)
    const int mtile = blockIdx.x >> 3;
    const int chunk = blockIdx.x & 7;
    const int m0 = mtile * 128;

    // stage this chunk's ||c||^2 into LDS (read once per block)
    for (int i = tid; i < CHUNK; i += 256)
        *(float*)(smem + SM_C2 + i * 4) = c2[chunk * CHUNK + i];

    float mv[16];
    int   mi[16];
    #pragma unroll
    for (int s = 0; s < 16; ++s) { mv[s] = 3.4e38f; mi[s] = 0; }

    for (int nt = 0; nt < 16; ++nt) {
        f32x4 acc[4][4];
        #pragma unroll
        for (int i = 0; i < 4; ++i)
            #pragma unroll
            for (int j = 0; j < 4; ++j) acc[i][j] = (f32x4)0.0f;

        for (int kit = 0; kit < 16; ++kit) {
            // stage 32KB (4 plane-tiles of 8KB); each wave stages one plane
            const u16* gsrc;
            if (wave < 2) {
                size_t off = ((size_t)(mtile * 16 + kit)) * 4096;
                gsrc = (wave == 0 ? xh : xl) + off;
            } else {
                size_t off = ((size_t)((chunk * 16 + nt) * 16 + kit)) * 4096;
                gsrc = (wave == 2 ? chh : cll) + off;
            }
            char* ldsbase = smem + wave * 8192;
            #pragma unroll
            for (int jj = 0; jj < 8; ++jj) {
                __builtin_amdgcn_global_load_lds(
                    (const __attribute__((address_space(1))) void*)(gsrc + jj * 512 + lane * 8),
                    (__attribute__((address_space(3))) void*)(ldsbase + jj * 1024),
                    16, 0, 0);
            }
            __syncthreads();

            const char* Ah = smem;
            const char* Al = smem + 8192;
            const char* Bh = smem + 16384;
            const char* Bl = smem + 24576;
            half8 ah[4], al[4];
            #pragma unroll
            for (int i = 0; i < 4; ++i) {
                int g = wm * 4 + i;
                ah[i] = *(const half8*)(Ah + g * 1024 + lane * 16);
                al[i] = *(const half8*)(Al + g * 1024 + lane * 16);
            }
            #pragma unroll
            for (int j = 0; j < 4; ++j) {
                int g = wn * 4 + j;
                half8 bh = *(const half8*)(Bh + g * 1024 + lane * 16);
                half8 bl = *(const half8*)(Bl + g * 1024 + lane * 16);
                #pragma unroll
                for (int i = 0; i < 4; ++i) {
                    acc[i][j] = __builtin_amdgcn_mfma_f32_16x16x32_f16(ah[i], bh, acc[i][j], 0, 0, 0);
                    acc[i][j] = __builtin_amdgcn_mfma_f32_16x16x32_f16(ah[i], bl, acc[i][j], 0, 0, 0);
                    acc[i][j] = __builtin_amdgcn_mfma_f32_16x16x32_f16(al[i], bh, acc[i][j], 0, 0, 0);
                }
            }
            __syncthreads();
        }

        // epilogue: score = ||c||^2 - acc/128  (acc = 256 * x.c; -2/256)
        // candidates arrive in strictly increasing code id -> '<' keeps first.
        #pragma unroll
        for (int j = 0; j < 4; ++j) {
            int ncol = nt * 128 + wn * 64 + j * 16 + (lane & 15);
            float cv = *(const float*)(smem + SM_C2 + ncol * 4);
            int gid = chunk * CHUNK + ncol;
            #pragma unroll
            for (int i = 0; i < 4; ++i)
                #pragma unroll
                for (int r = 0; r < 4; ++r) {
                    float s = fmaf(acc[i][j][r], -0.0078125f, cv);
                    int slot = i * 4 + r;
                    if (s < mv[slot]) { mv[slot] = s; mi[slot] = gid; }
                }
        }
    }

    // block reduction: 32 contributors per row (16 cols x 2 wn-waves)
    // scratch layout: entry(contrib, row) at contrib*1032 + row*8 (pad vs banks)
    {
        int contrib = wn * 16 + (lane & 15);
        #pragma unroll
        for (int i = 0; i < 4; ++i)
            #pragma unroll
            for (int r = 0; r < 4; ++r) {
                int row = wm * 64 + i * 16 + ((lane >> 4) & 3) * 4 + r;
                int2 e;
                e.x = __float_as_int(mv[i * 4 + r]);
                e.y = mi[i * 4 + r];
                *(int2*)(smem + contrib * 1032 + row * 8) = e;
            }
    }
    __syncthreads();
    if (tid < 128) {
        int2 e = *(const int2*)(smem + tid * 8);
        float bv = __int_as_float(e.x);
        int bi = e.y;
        for (int k = 1; k < 32; ++k) {
            int2 t2 = *(const int2*)(smem + k * 1032 + tid * 8);
            float v = __int_as_float(t2.x);
            if (v < bv || (v == bv && t2.y < bi)) { bv = v; bi = t2.y; }
        }
        pmin[(size_t)(m0 + tid) * NCHUNK + chunk] = bv;
        pid [(size_t)(m0 + tid) * NCHUNK + chunk] = bi;
    }
}

// ---------------- kernel 4: finalize (one wave per token) -------------------
__global__ __launch_bounds__(256) void nn_fin(const float* __restrict__ x,
                                              const float* __restrict__ pmin,
                                              const int* __restrict__ pid,
                                              int* __restrict__ out) {
    int w = threadIdx.x >> 6;
    int lane = threadIdx.x & 63;
    int t = blockIdx.x * 4 + w;
    const float* p = x + (size_t)t * DDIM + lane * 8;
    float4 v0 = *(const float4*)p;
    float4 v1 = *(const float4*)(p + 4);
    float s = v0.x*v0.x + v0.y*v0.y + v0.z*v0.z + v0.w*v0.w
            + v1.x*v1.x + v1.y*v1.y + v1.z*v1.z + v1.w*v1.w;
    #pragma unroll
    for (int off = 32; off > 0; off >>= 1) s += __shfl_down(s, off);
    if (lane == 0) {
        const float* pm = pmin + (size_t)t * NCHUNK;
        const int*   pi = pid  + (size_t)t * NCHUNK;
        float bv = pm[0]; int bi = pi[0];
        #pragma unroll
        for (int c = 1; c < NCHUNK; ++c) {
            float v = pm[c]; int id = pi[c];
            if (v < bv || (v == bv && id < bi)) { bv = v; bi = id; }
        }
        float mind = s + bv;   // ||x||^2 + min(||c||^2 - 2 x.c)
        out[t] = (mind <= DIST_THR) ? bi : -1;
    }
}

extern "C" void kernel_launch(void* const* d_in, const int* in_sizes, int n_in,
                              void* d_out, int out_size, void* d_ws, size_t ws_size,
                              hipStream_t stream) {
    const float* x     = (const float*)d_in[0];
    const float* codes = (const float*)d_in[1];
    int* out = (int*)d_out;

    // workspace layout (bytes):
    //  xh 8MB | xl 8MB | ch 16MB | cl 16MB | c2 64KB | pmin 256KB | pid 256KB
    char* ws = (char*)d_ws;
    u16*   xh   = (u16*)(ws);
    u16*   xl   = (u16*)(ws + 8388608);
    u16*   chh  = (u16*)(ws + 16777216);
    u16*   cll  = (u16*)(ws + 33554432);
    float* c2   = (float*)(ws + 50331648);
    float* pmin = (float*)(ws + 50397184);
    int*   pid  = (int*)  (ws + 50659328);

    nn_conv<<<NTOK   * 64 / 256, 256, 0, stream>>>(x, xh, xl);
    nn_conv<<<NCODES * 64 / 256, 256, 0, stream>>>(codes, chh, cll);
    nn_c2<<<NCODES / 4, 256, 0, stream>>>(codes, c2);
    nn_gemm<<<64 * NCHUNK, 256, 0, stream>>>(xh, xl, chh, cll, c2, pmin, pid);
    nn_fin<<<NTOK / 4, 256, 0, stream>>>(x, pmin, pid, out);
}